// Round 5
// baseline (847.485 us; speedup 1.0000x reference)
//
#include <hip/hip_runtime.h>

#define N_NODES 50000
#define N_EDGES 800000
#define NODE_DIM 128
#define EDGE_DIM 64
#define HIDDEN 256
#define K_E 320   // 2*NODE_DIM + EDGE_DIM
#define K_N 192   // NODE_DIM + EDGE_DIM

typedef __attribute__((ext_vector_type(8))) short bf16x8;
typedef __attribute__((ext_vector_type(4))) float f32x4;
typedef unsigned short u16;
typedef unsigned int u32;

#define MFMA __builtin_amdgcn_mfma_f32_16x16x32_bf16

__device__ inline u16 f2bf(float f) {
  u32 u = __builtin_bit_cast(u32, f);
  u += 0x7fffu + ((u >> 16) & 1u);
  return (u16)(u >> 16);
}
__device__ inline float bf2f(u16 u) {
  u32 x = ((u32)u) << 16;
  return __builtin_bit_cast(float, x);
}
__device__ inline u32 pack2(float a, float b) {
  return (u32)f2bf(a) | ((u32)f2bf(b) << 16);
}
__device__ inline void st_bf4(u16* p, float4 v) {
  ushort4 r;
  r.x = f2bf(v.x); r.y = f2bf(v.y); r.z = f2bf(v.z); r.w = f2bf(v.w);
  *reinterpret_cast<ushort4*>(p) = r;
}

// ---------------- weight prep ----------------
// fragfmt=1: w1x frag-order [kb][t][g][lr][jj] (A-operand, hidden-as-m);
//            w2x frag-order [kb2][t2][g][lr][jj] (A-operand, out-as-m); nfb written.
// fragfmt=0: w1x row-major [256][320]; w2x row-major [64][256]. (fallback)
__global__ void prep_weights(const float* __restrict__ We1, const float* __restrict__ We2,
                             const float* __restrict__ Wn1, const float* __restrict__ Wn2,
                             const float* __restrict__ nf,
                             u16* __restrict__ w1x, u16* __restrict__ w2x,
                             u16* __restrict__ wn1t, u16* __restrict__ wn2t,
                             u16* __restrict__ nfb, int fragfmt) {
  const int stride = gridDim.x * blockDim.x;
  const int tid = blockIdx.x * blockDim.x + threadIdx.x;
  for (int i = tid; i < HIDDEN * K_E; i += stride) {
    int h, k;
    if (fragfmt) {
      int jj = i & 7, lr = (i >> 3) & 15, g = (i >> 7) & 3, t = (i >> 9) & 15, kb = i >> 13;
      h = t * 16 + lr; k = kb * 32 + g * 8 + jj;
    } else { h = i / K_E; k = i % K_E; }
    w1x[i] = f2bf(We1[k * HIDDEN + h]);
  }
  for (int i = tid; i < EDGE_DIM * HIDDEN; i += stride) {
    int n, k;
    if (fragfmt) {
      int jj = i & 7, lr = (i >> 3) & 15, g = (i >> 7) & 3, t2 = (i >> 9) & 3, kb2 = (i >> 11) & 7;
      n = t2 * 16 + lr; k = kb2 * 32 + g * 8 + jj;
    } else { n = i / HIDDEN; k = i % HIDDEN; }
    w2x[i] = f2bf(We2[k * EDGE_DIM + n]);
  }
  for (int i = tid; i < HIDDEN * K_N; i += stride) {
    int n = i / K_N, k = i % K_N;
    wn1t[i] = f2bf(Wn1[k * HIDDEN + n]);
  }
  for (int i = tid; i < NODE_DIM * HIDDEN; i += stride) {
    int n = i / HIDDEN, k = i % HIDDEN;
    wn2t[i] = f2bf(Wn2[k * NODE_DIM + n]);
  }
  if (fragfmt) {
    const float4* nf4 = reinterpret_cast<const float4*>(nf);
    for (int i = tid; i < N_NODES * NODE_DIM / 4; i += stride)
      st_bf4(&nfb[i * 4], nf4[i]);
  }
}

// ---------------- CSR build ----------------
__global__ void hist_kernel(const int* __restrict__ dst, int* __restrict__ hist) {
  int e = blockIdx.x * blockDim.x + threadIdx.x;
  if (e < N_EDGES) atomicAdd(&hist[dst[e]], 1);
}

#define SCAN_T 256
#define SCAN_ITEMS 196  // 256*196 = 50176 >= 50000
__global__ void scan_kernel(const int* __restrict__ hist, int* __restrict__ off,
                            int* __restrict__ cursor) {
  __shared__ int ssum[SCAN_T];
  const int tid = threadIdx.x;
  const int base = tid * SCAN_ITEMS;
  int s = 0;
  for (int i = 0; i < SCAN_ITEMS; ++i) {
    int idx = base + i;
    s += (idx < N_NODES) ? hist[idx] : 0;
  }
  ssum[tid] = s;
  __syncthreads();
  for (int d = 1; d < SCAN_T; d <<= 1) {
    int t = (tid >= d) ? ssum[tid - d] : 0;
    __syncthreads();
    ssum[tid] += t;
    __syncthreads();
  }
  int run = ssum[tid] - s;  // exclusive prefix
  for (int i = 0; i < SCAN_ITEMS; ++i) {
    int idx = base + i;
    if (idx < N_NODES) {
      off[idx] = run;
      cursor[idx] = run;
      run += hist[idx];
    }
  }
  if (tid == SCAN_T - 1) off[N_NODES] = run;
}

// eid[pos] = edge id  (CSR permutation; e_upd itself stays in edge order)
__global__ void scatter_kernel(const int* __restrict__ dst, int* __restrict__ cursor,
                               int* __restrict__ eid) {
  int e = blockIdx.x * blockDim.x + threadIdx.x;
  if (e < N_EDGES) eid[atomicAdd(&cursor[dst[e]], 1)] = e;
}

// ---------------- edge MLP v4: operand-swapped, 2 edge-sets per wave ----------------
// 512 thr = 8 waves; 32 edges/wave (2 register sets of 16), 256 edges/block.
// Per kb: 16 W-frag ds_read_b128 feed 32 MFMAs (2x the R4 ratio).
// LDS 32KB: phase 1 = W1 kb-tile double buffer (2x16KB); phase 2 = per-wave 4KB
// H-bounce slot, layer 2 in two k-halves per edge-set.
__global__ __launch_bounds__(512, 2) void edge_mlp(
    const u16* __restrict__ nfb, const float* __restrict__ ef,
    const int* __restrict__ src, const int* __restrict__ dst,
    const u16* __restrict__ w1f, const float* __restrict__ b1,
    const u16* __restrict__ w2f, const float* __restrict__ b2,
    u16* __restrict__ e_upd, float* __restrict__ out_edge)
{
  __shared__ u16 W[16384];   // 32KB

  const int tid = threadIdx.x;
  const int wv = tid >> 6, lane = tid & 63;
  const int er = lane & 15;      // edge index within 16-set (n-col of D')
  const int g  = lane >> 4;      // k-group
  const int e0 = blockIdx.x * 256;
  const int egA = e0 + wv * 32 + er;
  const int egB = egA + 16;

  // ---- fused edge-feature passthrough (fp32), fully coalesced ----
  {
    const float4* ef4 = reinterpret_cast<const float4*>(ef);
    float4* oe4 = reinterpret_cast<float4*>(out_edge);
    #pragma unroll
    for (int p = 0; p < 8; ++p) {
      size_t i = (size_t)e0 * 16 + p * 512 + tid;
      oe4[i] = ef4[i];
    }
  }

  // ---- gather both edge-sets' concat features into B-operand fragments ----
  const int sA = src[egA] << 7, dA = dst[egA] << 7;
  const int sB = src[egB] << 7, dB = dst[egB] << 7;
  bf16x8 efA[10], efB[10];
  #pragma unroll
  for (int kb = 0; kb < 4; ++kb) {
    efA[kb] = *reinterpret_cast<const bf16x8*>(nfb + sA + kb * 32 + g * 8);
    efB[kb] = *reinterpret_cast<const bf16x8*>(nfb + sB + kb * 32 + g * 8);
  }
  #pragma unroll
  for (int kb = 0; kb < 2; ++kb) {
    const float* epA = ef + (size_t)egA * 64 + kb * 32 + g * 8;
    const float* epB = ef + (size_t)egB * 64 + kb * 32 + g * 8;
    float4 lo, hi;
    bf16x8 v;
    lo = *reinterpret_cast<const float4*>(epA);
    hi = *reinterpret_cast<const float4*>(epA + 4);
    v[0] = (short)f2bf(lo.x); v[1] = (short)f2bf(lo.y);
    v[2] = (short)f2bf(lo.z); v[3] = (short)f2bf(lo.w);
    v[4] = (short)f2bf(hi.x); v[5] = (short)f2bf(hi.y);
    v[6] = (short)f2bf(hi.z); v[7] = (short)f2bf(hi.w);
    efA[4 + kb] = v;
    lo = *reinterpret_cast<const float4*>(epB);
    hi = *reinterpret_cast<const float4*>(epB + 4);
    v[0] = (short)f2bf(lo.x); v[1] = (short)f2bf(lo.y);
    v[2] = (short)f2bf(lo.z); v[3] = (short)f2bf(lo.w);
    v[4] = (short)f2bf(hi.x); v[5] = (short)f2bf(hi.y);
    v[6] = (short)f2bf(hi.z); v[7] = (short)f2bf(hi.w);
    efB[4 + kb] = v;
  }
  #pragma unroll
  for (int kb = 0; kb < 4; ++kb) {
    efA[6 + kb] = *reinterpret_cast<const bf16x8*>(nfb + dA + kb * 32 + g * 8);
    efB[6 + kb] = *reinterpret_cast<const bf16x8*>(nfb + dB + kb * 32 + g * 8);
  }

  // ---- layer-1 acc init with bias ----
  f32x4 accA[16], accB[16];
  #pragma unroll
  for (int t = 0; t < 16; ++t) {
    f32x4 bv = *reinterpret_cast<const f32x4*>(b1 + t * 16 + g * 4);
    accA[t] = bv;
    accB[t] = bv;
  }

  // ---- layer 1: H'[hidden][edge] = W1(A) x edges(B), W1 LDS double-buffered ----
  const uint4* w1s4 = reinterpret_cast<const uint4*>(w1f);
  {
    uint4* d4 = reinterpret_cast<uint4*>(W);
    d4[tid] = w1s4[tid];
    d4[tid + 512] = w1s4[tid + 512];
  }
  __syncthreads();

  #pragma unroll
  for (int kb = 0; kb < 10; ++kb) {
    uint4 nv0, nv1;
    if (kb < 9) {   // issue next-tile loads early (hide L2 latency under MFMAs)
      nv0 = w1s4[(kb + 1) * 1024 + tid];
      nv1 = w1s4[(kb + 1) * 1024 + tid + 512];
    }
    const u16* Wc = W + (kb & 1) * 8192;
    #pragma unroll
    for (int t = 0; t < 16; ++t) {
      bf16x8 wf = *reinterpret_cast<const bf16x8*>(Wc + ((t * 4 + g) * 16 + er) * 8);
      accA[t] = MFMA(wf, efA[kb], accA[t], 0, 0, 0);
      accB[t] = MFMA(wf, efB[kb], accB[t], 0, 0, 0);
    }
    if (kb < 9) {
      uint4* d4 = reinterpret_cast<uint4*>(W + ((kb + 1) & 1) * 8192);
      d4[tid] = nv0;
      d4[tid + 512] = nv1;
    }
    __syncthreads();
  }

  // ---- per-wave 4KB H bounce + layer 2 (operand-swapped) per edge-set ----
  u16* hb = W + wv * 2048;   // 2048 u16 = 4KB per-wave slot

  #pragma unroll
  for (int set = 0; set < 2; ++set) {
    const f32x4* acc = set ? accB : accA;

    // layer-2 acc init with bias
    f32x4 acc2[4];
    #pragma unroll
    for (int t2 = 0; t2 < 4; ++t2)
      acc2[t2] = *reinterpret_cast<const f32x4*>(b2 + t2 * 16 + g * 4);

    #pragma unroll
    for (int ph = 0; ph < 2; ++ph) {
      // write H half: t = ph*8 .. ph*8+7 (hidden ph*128 .. ph*128+127)
      #pragma unroll
      for (int tt = 0; tt < 8; ++tt) {
        int t = ph * 8 + tt;
        u32 pk0 = pack2(fmaxf(acc[t][0], 0.f), fmaxf(acc[t][1], 0.f));
        u32 pk1 = pack2(fmaxf(acc[t][2], 0.f), fmaxf(acc[t][3], 0.f));
        int aloc = tt >> 1;                  // local kb2 (0..3)
        int gp = (t & 1) * 2 + (g >> 1);
        int unit = (aloc * 4 + gp) * 16 + er;
        uint2 pv; pv.x = pk0; pv.y = pk1;
        *reinterpret_cast<uint2*>(hb + unit * 8 + (g & 1) * 4) = pv;
      }

      // consume: kb2 = ph*4 .. ph*4+3
      #pragma unroll
      for (int kl = 0; kl < 4; ++kl) {
        int kb2 = ph * 4 + kl;
        bf16x8 hf = *reinterpret_cast<const bf16x8*>(hb + ((kl * 4 + g) * 16 + er) * 8);
        #pragma unroll
        for (int t2 = 0; t2 < 4; ++t2) {
          bf16x8 wf2 = *reinterpret_cast<const bf16x8*>(
              w2f + (((kb2 * 4 + t2) * 4 + g) * 16 + er) * 8);
          acc2[t2] = MFMA(wf2, hf, acc2[t2], 0, 0, 0);
        }
      }
    }

    // direct edge-order store: lane holds 4 consecutive out-cols for edge er
    const size_t erow = (size_t)(e0 + wv * 32 + set * 16 + er);
    #pragma unroll
    for (int t2 = 0; t2 < 4; ++t2) {
      uint2 pv;
      pv.x = pack2(acc2[t2][0], acc2[t2][1]);
      pv.y = pack2(acc2[t2][2], acc2[t2][3]);
      *reinterpret_cast<uint2*>(e_upd + erow * 64 + t2 * 16 + g * 4) = pv;
    }
  }
}

// ---------------- edge MLP fallback (R2 structure, edge-order output) ----------------
#define SA_E 328
#define SH   264

__global__ __launch_bounds__(512) void edge_old(
    const float* __restrict__ nf, const float* __restrict__ ef,
    const int* __restrict__ src, const int* __restrict__ dst,
    const u16* __restrict__ w1, const float* __restrict__ b1,
    const u16* __restrict__ w2, const float* __restrict__ b2,
    u16* __restrict__ e_upd, float* __restrict__ out_edge)
{
  __shared__ u16 A[64 * SA_E];
  __shared__ u16 H2[64 * 68];
  __shared__ int sidx[64], didx[64];
  const int tid = threadIdx.x;
  const int e0 = blockIdx.x * 64;

  if (tid < 64) {
    sidx[tid] = src[e0 + tid];
    didx[tid] = dst[e0 + tid];
  }
  __syncthreads();

  const float4* nf4 = reinterpret_cast<const float4*>(nf);
  const float4* ef4 = reinterpret_cast<const float4*>(ef);
  float4* oe4 = reinterpret_cast<float4*>(out_edge);

  #pragma unroll
  for (int p = 0; p < 4; ++p) {
    int i = p * 512 + tid;
    int row = i >> 5, c4 = i & 31;
    float4 v = nf4[(size_t)sidx[row] * 32 + c4];
    st_bf4(&A[row * SA_E + c4 * 4], v);
  }
  #pragma unroll
  for (int p = 0; p < 2; ++p) {
    int i = p * 512 + tid;
    int row = i >> 4, c4 = i & 15;
    size_t gidx = (size_t)(e0 + row) * 16 + c4;
    float4 v = ef4[gidx];
    oe4[gidx] = v;
    st_bf4(&A[row * SA_E + 128 + c4 * 4], v);
  }
  #pragma unroll
  for (int p = 0; p < 4; ++p) {
    int i = p * 512 + tid;
    int row = i >> 5, c4 = i & 31;
    float4 v = nf4[(size_t)didx[row] * 32 + c4];
    st_bf4(&A[row * SA_E + 192 + c4 * 4], v);
  }
  __syncthreads();

  const int wave = tid >> 6, lane = tid & 63;
  const int lr = lane & 15;
  const int lk = (lane >> 4) * 8;

  const int wr = wave >> 1;
  const int wc = wave & 1;
  f32x4 acc[8] = {};
  for (int kb = 0; kb < K_E / 32; ++kb) {
    const int ko = kb * 32 + lk;
    bf16x8 a = *reinterpret_cast<const bf16x8*>(&A[(wr * 16 + lr) * SA_E + ko]);
    #pragma unroll
    for (int nt = 0; nt < 8; ++nt) {
      bf16x8 b = *reinterpret_cast<const bf16x8*>(
          &w1[(size_t)(wc * 128 + nt * 16 + lr) * K_E + ko]);
      acc[nt] = MFMA(a, b, acc[nt], 0, 0, 0);
    }
  }
  __syncthreads();

  u16* H = A;
  #pragma unroll
  for (int nt = 0; nt < 8; ++nt) {
    int col = wc * 128 + nt * 16 + lr;
    float bias = b1[col];
    #pragma unroll
    for (int j = 0; j < 4; ++j) {
      int row = wr * 16 + (lane >> 4) * 4 + j;
      float h = acc[nt][j] + bias;
      H[row * SH + col] = f2bf(h > 0.f ? h : 0.f);
    }
  }
  __syncthreads();

  const int r2 = wave >> 1;
  const int c2 = wave & 1;
  f32x4 acc2[2] = {};
  for (int kb = 0; kb < HIDDEN / 32; ++kb) {
    const int ko = kb * 32 + lk;
    bf16x8 a = *reinterpret_cast<const bf16x8*>(&H[(r2 * 16 + lr) * SH + ko]);
    #pragma unroll
    for (int nt = 0; nt < 2; ++nt) {
      bf16x8 b = *reinterpret_cast<const bf16x8*>(
          &w2[(size_t)(c2 * 32 + nt * 16 + lr) * HIDDEN + ko]);
      acc2[nt] = MFMA(a, b, acc2[nt], 0, 0, 0);
    }
  }

  #pragma unroll
  for (int nt = 0; nt < 2; ++nt) {
    int col = c2 * 32 + nt * 16 + lr;
    float bias = b2[col];
    #pragma unroll
    for (int j = 0; j < 4; ++j) {
      int row = r2 * 16 + (lane >> 4) * 4 + j;
      H2[row * 68 + col] = f2bf(acc2[nt][j] + bias);
    }
  }
  __syncthreads();
  #pragma unroll
  for (int p = 0; p < 2; ++p) {
    int i = p * 512 + tid;
    int row = i >> 4, c = (i & 15) * 4;
    ushort4 v = *reinterpret_cast<ushort4*>(&H2[row * 68 + c]);
    *reinterpret_cast<ushort4*>(&e_upd[(size_t)(e0 + row) * 64 + c]) = v;
  }
}

// ---------------- node MLP + degree gate (CSR eid gather) ----------------
#define SA_N 200

__global__ __launch_bounds__(256) void node_kernel(
    const float* __restrict__ nf,
    const u16* __restrict__ e_upd, const int* __restrict__ off,
    const int* __restrict__ eid, const int* __restrict__ hist,
    const u16* __restrict__ w1, const float* __restrict__ b1,
    const u16* __restrict__ w2, const float* __restrict__ b2,
    float* __restrict__ hout)
{
  __shared__ u16 A[64 * SH];
  const int tid = threadIdx.x;
  const int n0 = blockIdx.x * 64;

  const float4* nf4 = reinterpret_cast<const float4*>(nf);

  #pragma unroll
  for (int p = 0; p < 8; ++p) {
    int i = p * 256 + tid;
    int row = i >> 5, c4 = i & 31;
    int rg = min(n0 + row, N_NODES - 1);
    float4 v = nf4[(size_t)rg * 32 + c4];
    st_bf4(&A[row * SA_N + c4 * 4], v);
  }

  {
    const int gg = tid >> 4, l16 = tid & 15;
    for (int row = gg; row < 64; row += 16) {
      int n = n0 + row;
      float4 accv = {0.f, 0.f, 0.f, 0.f};
      if (n < N_NODES) {
        int s0 = off[n], s1 = off[n + 1];
        for (int s = s0; s < s1; ++s) {
          int e = eid[s];
          ushort4 v = *reinterpret_cast<const ushort4*>(&e_upd[(size_t)e * 64 + l16 * 4]);
          accv.x += bf2f(v.x); accv.y += bf2f(v.y);
          accv.z += bf2f(v.z); accv.w += bf2f(v.w);
        }
      }
      st_bf4(&A[row * SA_N + 128 + l16 * 4], accv);
    }
  }
  __syncthreads();

  const int wave = tid >> 6, lane = tid & 63;
  const int lr = lane & 15;
  const int lk = (lane >> 4) * 8;

  f32x4 acc[4][4] = {};
  for (int kb = 0; kb < K_N / 32; ++kb) {
    const int ko = kb * 32 + lk;
    bf16x8 a[4], b[4];
    #pragma unroll
    for (int mt = 0; mt < 4; ++mt)
      a[mt] = *reinterpret_cast<const bf16x8*>(&A[(mt * 16 + lr) * SA_N + ko]);
    #pragma unroll
    for (int nt = 0; nt < 4; ++nt)
      b[nt] = *reinterpret_cast<const bf16x8*>(&w1[(size_t)(wave * 64 + nt * 16 + lr) * K_N + ko]);
    #pragma unroll
    for (int mt = 0; mt < 4; ++mt)
      #pragma unroll
      for (int nt = 0; nt < 4; ++nt)
        acc[mt][nt] = MFMA(a[mt], b[nt], acc[mt][nt], 0, 0, 0);
  }
  __syncthreads();

  u16* H = A;
  #pragma unroll
  for (int mt = 0; mt < 4; ++mt)
    #pragma unroll
    for (int nt = 0; nt < 4; ++nt) {
      int col = wave * 64 + nt * 16 + lr;
      float bias = b1[col];
      #pragma unroll
      for (int j = 0; j < 4; ++j) {
        int row = mt * 16 + (lane >> 4) * 4 + j;
        float h = acc[mt][nt][j] + bias;
        H[row * SH + col] = f2bf(h > 0.f ? h : 0.f);
      }
    }
  __syncthreads();

  f32x4 acc2[8] = {};
  for (int kb = 0; kb < HIDDEN / 32; ++kb) {
    const int ko = kb * 32 + lk;
    bf16x8 a = *reinterpret_cast<const bf16x8*>(&H[(wave * 16 + lr) * SH + ko]);
    #pragma unroll
    for (int nt = 0; nt < 8; ++nt) {
      bf16x8 b = *reinterpret_cast<const bf16x8*>(&w2[(size_t)(nt * 16 + lr) * HIDDEN + ko]);
      acc2[nt] = MFMA(a, b, acc2[nt], 0, 0, 0);
    }
  }
  #pragma unroll
  for (int nt = 0; nt < 8; ++nt) {
    int col = nt * 16 + lr;
    float bias = b2[col];
    #pragma unroll
    for (int j = 0; j < 4; ++j) {
      int row = wave * 16 + (lane >> 4) * 4 + j;
      int rg = n0 + row;
      if (rg < N_NODES) {
        float v = acc2[nt][j] + bias;
        hout[(size_t)rg * NODE_DIM + col] =
            (hist[rg] != 0) ? v : nf[(size_t)rg * NODE_DIM + col];
      }
    }
  }
}

// ---------------- launcher ----------------
extern "C" void kernel_launch(void* const* d_in, const int* in_sizes, int n_in,
                              void* d_out, int out_size, void* d_ws, size_t ws_size,
                              hipStream_t stream) {
  const float* nf  = (const float*)d_in[0];
  const float* ef  = (const float*)d_in[1];
  const int*   src = (const int*)d_in[2];
  const int*   dst = (const int*)d_in[3];
  const float* We1 = (const float*)d_in[4];
  const float* be1 = (const float*)d_in[5];
  const float* We2 = (const float*)d_in[6];
  const float* be2 = (const float*)d_in[7];
  const float* Wn1 = (const float*)d_in[8];
  const float* bn1 = (const float*)d_in[9];
  const float* Wn2 = (const float*)d_in[10];
  const float* bn2 = (const float*)d_in[11];

  float* hout = (float*)d_out;
  float* out_edge = hout + (size_t)N_NODES * NODE_DIM;

  char* ws = (char*)d_ws;
  int* hist    = (int*)ws;                       // 200,000 B
  int* off     = (int*)(ws + 200000);            // 200,004 B
  int* cursor  = (int*)(ws + 400016);            // 200,000 B
  int* eid     = (int*)(ws + 600016);            // 3,200,000 B
  u16* e_upd   = (u16*)(ws + 3800016);           // 102,400,000 B
  u16* w1x     = (u16*)(ws + 106200016);         // 163,840 B
  u16* w2x     = (u16*)(ws + 106363856);         // 32,768 B
  u16* wn1t    = (u16*)(ws + 106396624);         // 98,304 B
  u16* wn2t    = (u16*)(ws + 106494928);         // 65,536 B
  u16* nfb     = (u16*)(ws + 106560464);         // 12,800,000 B
  const size_t NEED_NEW = 119360464;
  int fragfmt = (ws_size >= NEED_NEW) ? 1 : 0;

  hipMemsetAsync(hist, 0, 200000, stream);
  prep_weights<<<512, 256, 0, stream>>>(We1, We2, Wn1, Wn2, nf, w1x, w2x, wn1t, wn2t,
                                        fragfmt ? nfb : wn2t /*unused*/, fragfmt);
  hist_kernel<<<(N_EDGES + 255) / 256, 256, 0, stream>>>(dst, hist);
  scan_kernel<<<1, SCAN_T, 0, stream>>>(hist, off, cursor);
  scatter_kernel<<<(N_EDGES + 255) / 256, 256, 0, stream>>>(dst, cursor, eid);

  if (fragfmt) {
    edge_mlp<<<N_EDGES / 256, 512, 0, stream>>>(nfb, ef, src, dst, w1x, be1, w2x, be2,
                                                e_upd, out_edge);
  } else {
    edge_old<<<N_EDGES / 64, 512, 0, stream>>>(nf, ef, src, dst, w1x, be1, w2x, be2,
                                               e_upd, out_edge);
  }
  node_kernel<<<(N_NODES + 63) / 64, 256, 0, stream>>>(nf, e_upd, off, eid, hist,
                                                       wn1t, bn1, wn2t, bn2, hout);
}

// Round 6
// 744.627 us; speedup vs baseline: 1.1381x; 1.1381x over previous
//
#include <hip/hip_runtime.h>

#define N_NODES 50000
#define N_EDGES 800000
#define NODE_DIM 128
#define EDGE_DIM 64
#define HIDDEN 256
#define K_E 320   // 2*NODE_DIM + EDGE_DIM
#define K_N 192   // NODE_DIM + EDGE_DIM

typedef __attribute__((ext_vector_type(8))) short bf16x8;
typedef __attribute__((ext_vector_type(4))) float f32x4;
typedef __attribute__((ext_vector_type(16))) float f32x16;
typedef unsigned short u16;
typedef unsigned int u32;

#define MFMA16 __builtin_amdgcn_mfma_f32_16x16x32_bf16
#define MFMA32 __builtin_amdgcn_mfma_f32_32x32x16_bf16

__device__ inline u16 f2bf(float f) {
  u32 u = __builtin_bit_cast(u32, f);
  u += 0x7fffu + ((u >> 16) & 1u);
  return (u16)(u >> 16);
}
__device__ inline float bf2f(u16 u) {
  u32 x = ((u32)u) << 16;
  return __builtin_bit_cast(float, x);
}
__device__ inline u32 pack2(float a, float b) {
  return (u32)f2bf(a) | ((u32)f2bf(b) << 16);
}
__device__ inline void st_bf4(u16* p, float4 v) {
  ushort4 r;
  r.x = f2bf(v.x); r.y = f2bf(v.y); r.z = f2bf(v.z); r.w = f2bf(v.w);
  *reinterpret_cast<ushort4*>(p) = r;
}

// ---------------- weight prep ----------------
// w1y: 32x32x16 A-frag order, ht-major: [ht][kb][lane][jj], h=ht*32+(l&31),
//      k=kb*16+(l>>5)*8+jj.   (256*320 = 81920 elems)
// w2y: layer-2 A-frag order with pi-permuted k so layer-1 D rows feed B-frags
//      in-register: [kb2][t2][lane][jj], out=t2*32+(l&31),
//      k=kb2*16 + (jj&3) + 8*(jj>>2) + 4*(l>>5).   (64*256 = 16384 elems)
// wn1t/wn2t: row-major [N][K] bf16 for the 16x16 node MLP.  nfb: bf16 node table.
__global__ void prep_weights(const float* __restrict__ We1, const float* __restrict__ We2,
                             const float* __restrict__ Wn1, const float* __restrict__ Wn2,
                             const float* __restrict__ nf,
                             u16* __restrict__ w1y, u16* __restrict__ w2y,
                             u16* __restrict__ wn1t, u16* __restrict__ wn2t,
                             u16* __restrict__ nfb) {
  const int stride = gridDim.x * blockDim.x;
  const int tid = blockIdx.x * blockDim.x + threadIdx.x;
  for (int i = tid; i < HIDDEN * K_E; i += stride) {
    int jj = i & 7;
    int l = (i >> 3) & 63;
    int rem = i % 10240;          // 10240 = 20*64*8 per ht
    int kb = rem >> 9;            // rem / 512
    int ht = i / 10240;
    int h = ht * 32 + (l & 31);
    int k = kb * 16 + (l >> 5) * 8 + jj;
    w1y[i] = f2bf(We1[k * HIDDEN + h]);
  }
  for (int i = tid; i < EDGE_DIM * HIDDEN; i += stride) {
    int jj = i & 7;
    int l = (i >> 3) & 63;
    int t2 = (i >> 9) & 1;
    int kb2 = i >> 10;
    int out = t2 * 32 + (l & 31);
    int hi = l >> 5;
    int k = kb2 * 16 + (jj & 3) + 8 * (jj >> 2) + 4 * hi;   // pi permutation
    w2y[i] = f2bf(We2[k * EDGE_DIM + out]);
  }
  for (int i = tid; i < HIDDEN * K_N; i += stride) {
    int n = i / K_N, k = i % K_N;
    wn1t[i] = f2bf(Wn1[k * HIDDEN + n]);
  }
  for (int i = tid; i < NODE_DIM * HIDDEN; i += stride) {
    int n = i / HIDDEN, k = i % HIDDEN;
    wn2t[i] = f2bf(Wn2[k * NODE_DIM + n]);
  }
  {
    const float4* nf4 = reinterpret_cast<const float4*>(nf);
    for (int i = tid; i < N_NODES * NODE_DIM / 4; i += stride)
      st_bf4(&nfb[i * 4], nf4[i]);
  }
}

// ---------------- CSR build ----------------
__global__ void hist_kernel(const int* __restrict__ dst, int* __restrict__ hist) {
  int e = blockIdx.x * blockDim.x + threadIdx.x;
  if (e < N_EDGES) atomicAdd(&hist[dst[e]], 1);
}

#define SCAN_T 256
#define SCAN_ITEMS 196  // 256*196 = 50176 >= 50000
__global__ void scan_kernel(const int* __restrict__ hist, int* __restrict__ off,
                            int* __restrict__ cursor) {
  __shared__ int ssum[SCAN_T];
  const int tid = threadIdx.x;
  const int base = tid * SCAN_ITEMS;
  int s = 0;
  for (int i = 0; i < SCAN_ITEMS; ++i) {
    int idx = base + i;
    s += (idx < N_NODES) ? hist[idx] : 0;
  }
  ssum[tid] = s;
  __syncthreads();
  for (int d = 1; d < SCAN_T; d <<= 1) {
    int t = (tid >= d) ? ssum[tid - d] : 0;
    __syncthreads();
    ssum[tid] += t;
    __syncthreads();
  }
  int run = ssum[tid] - s;  // exclusive prefix
  for (int i = 0; i < SCAN_ITEMS; ++i) {
    int idx = base + i;
    if (idx < N_NODES) {
      off[idx] = run;
      cursor[idx] = run;
      run += hist[idx];
    }
  }
  if (tid == SCAN_T - 1) off[N_NODES] = run;
}

__global__ void scatter_kernel(const int* __restrict__ dst, int* __restrict__ cursor,
                               int* __restrict__ eid) {
  int e = blockIdx.x * blockDim.x + threadIdx.x;
  if (e < N_EDGES) eid[atomicAdd(&cursor[dst[e]], 1)] = e;
}

// ---------------- edge MLP v5: 32x32 MFMA, ht-outer, in-register L1->L2 chain --
// 256 thr = 4 waves x 32 edges = 128 edges/block; grid 6250.
// Per (ht,kb): ONE 1KB W-frag ds_read feeds ONE 32x32x16 MFMA (32 FLOP/LDS-B).
// Layer 2 consumes each ht's acc in-register (pi-permuted W2) -> no H bounce.
// LDS: W1 per-ht double buffer 2x20KB; final C bounce aliases buffer 0.
__global__ __launch_bounds__(256, 3) void edge_mlp(
    const u16* __restrict__ nfb, const float* __restrict__ ef,
    const int* __restrict__ src, const int* __restrict__ dst,
    const u16* __restrict__ w1y, const float* __restrict__ b1,
    const u16* __restrict__ w2y, const float* __restrict__ b2,
    u16* __restrict__ e_upd, float* __restrict__ out_edge)
{
  __shared__ u16 W1s[2][10240];   // 40KB total

  const int tid = threadIdx.x;
  const int wv = tid >> 6, lane = tid & 63;
  const int ecol = lane & 31;     // edge within wave tile (D col)
  const int hi = lane >> 5;       // k half
  const int e0 = blockIdx.x * 128;
  const int eg = e0 + wv * 32 + ecol;

  // ---- fused edge-feature passthrough (fp32), fully coalesced ----
  {
    const float4* ef4 = reinterpret_cast<const float4*>(ef);
    float4* oe4 = reinterpret_cast<float4*>(out_edge);
    #pragma unroll
    for (int p = 0; p < 8; ++p) {
      size_t i = (size_t)e0 * 16 + p * 256 + tid;
      oe4[i] = ef4[i];
    }
  }

  // ---- gather edge concat features into B-frags (k = kb*16 + hi*8 + jj) ----
  const int si = src[eg] << 7;
  const int di = dst[eg] << 7;
  bf16x8 efr[20];
  #pragma unroll
  for (int kb = 0; kb < 8; ++kb)
    efr[kb] = *reinterpret_cast<const bf16x8*>(nfb + si + kb * 16 + hi * 8);
  #pragma unroll
  for (int kb = 0; kb < 4; ++kb) {
    const float* ep = ef + (size_t)eg * 64 + kb * 16 + hi * 8;
    float4 lo = *reinterpret_cast<const float4*>(ep);
    float4 hv = *reinterpret_cast<const float4*>(ep + 4);
    bf16x8 v;
    v[0] = (short)f2bf(lo.x); v[1] = (short)f2bf(lo.y);
    v[2] = (short)f2bf(lo.z); v[3] = (short)f2bf(lo.w);
    v[4] = (short)f2bf(hv.x); v[5] = (short)f2bf(hv.y);
    v[6] = (short)f2bf(hv.z); v[7] = (short)f2bf(hv.w);
    efr[8 + kb] = v;
  }
  #pragma unroll
  for (int kb = 0; kb < 8; ++kb)
    efr[12 + kb] = *reinterpret_cast<const bf16x8*>(nfb + di + kb * 16 + hi * 8);

  // ---- prologue: stage W1[ht=0] (20KB) ----
  {
    const uint4* s = reinterpret_cast<const uint4*>(w1y);
    uint4* d = reinterpret_cast<uint4*>(W1s[0]);
    #pragma unroll
    for (int j = 0; j < 5; ++j) d[tid + j * 256] = s[tid + j * 256];
  }
  __syncthreads();

  // ---- layer-2 accumulators, bias-initialized (D row map) ----
  f32x16 acc2[2];
  #pragma unroll
  for (int t2 = 0; t2 < 2; ++t2)
    #pragma unroll
    for (int r = 0; r < 16; ++r)
      acc2[t2][r] = b2[t2 * 32 + (r & 3) + 8 * (r >> 2) + 4 * hi];

  // ---- ht loop: 8 tiles of 32 hidden ----
  #pragma unroll
  for (int ht = 0; ht < 8; ++ht) {
    uint4 st[5];
    if (ht < 7) {   // issue next-tile loads early
      const uint4* s = reinterpret_cast<const uint4*>(w1y + (ht + 1) * 10240);
      #pragma unroll
      for (int j = 0; j < 5; ++j) st[j] = s[tid + j * 256];
    }

    // layer 1: acc[h(32) x e(32)] over K=320
    f32x16 acc;
    #pragma unroll
    for (int r = 0; r < 16; ++r)
      acc[r] = b1[ht * 32 + (r & 3) + 8 * (r >> 2) + 4 * hi];
    const u16* Wb = W1s[ht & 1];
    #pragma unroll
    for (int kb = 0; kb < 20; ++kb) {
      bf16x8 wf = *reinterpret_cast<const bf16x8*>(Wb + (kb * 64 + lane) * 8);
      acc = MFMA32(wf, efr[kb], acc, 0, 0, 0);
    }

    // layer 2: relu+pack acc rows -> B-frag slots (pi matches D row layout)
    #pragma unroll
    for (int s2 = 0; s2 < 2; ++s2) {
      bf16x8 hf;
      u32* hw = reinterpret_cast<u32*>(&hf);
      #pragma unroll
      for (int m = 0; m < 4; ++m)
        hw[m] = pack2(fmaxf(acc[s2 * 8 + 2 * m], 0.f),
                      fmaxf(acc[s2 * 8 + 2 * m + 1], 0.f));
      #pragma unroll
      for (int t2 = 0; t2 < 2; ++t2) {
        bf16x8 wf2 = *reinterpret_cast<const bf16x8*>(
            w2y + ((size_t)((ht * 2 + s2) * 2 + t2) * 64 + lane) * 8);
        acc2[t2] = MFMA32(wf2, hf, acc2[t2], 0, 0, 0);
      }
    }

    if (ht < 7) {   // write next tile, one barrier per ht
      uint4* d = reinterpret_cast<uint4*>(W1s[(ht + 1) & 1]);
      #pragma unroll
      for (int j = 0; j < 5; ++j) d[tid + j * 256] = st[j];
      __syncthreads();
    }
  }

  // ---- per-wave bounce (aliases W1s buf0; ht=7 read buf1 -> disjoint) ----
  u16* hb = reinterpret_cast<u16*>(W1s) + wv * 2304;   // 32 rows x 72 u16
  #pragma unroll
  for (int t2 = 0; t2 < 2; ++t2)
    #pragma unroll
    for (int m = 0; m < 8; ++m) {
      int rowb = 2 * (m & 1) + 8 * (m >> 1) + 4 * hi;   // rows rowb, rowb+1
      *reinterpret_cast<u32*>(hb + ecol * 72 + t2 * 32 + rowb) =
          pack2(acc2[t2][2 * m], acc2[t2][2 * m + 1]);
    }
  // same-wave ds_write -> ds_read: compiler inserts lgkmcnt wait
  {
    int er = lane >> 1, half = lane & 1;
    const u16* rp = hb + er * 72 + half * 32;
    uint4 o0 = *reinterpret_cast<const uint4*>(rp + 0);
    uint4 o1 = *reinterpret_cast<const uint4*>(rp + 8);
    uint4 o2 = *reinterpret_cast<const uint4*>(rp + 16);
    uint4 o3 = *reinterpret_cast<const uint4*>(rp + 24);
    uint4* dp = reinterpret_cast<uint4*>(
        e_upd + (size_t)(e0 + wv * 32 + er) * 64 + half * 32);
    dp[0] = o0; dp[1] = o1; dp[2] = o2; dp[3] = o3;
  }
}

// ---------------- per-node message sum (CSR gather), high-grid ----------------
__global__ __launch_bounds__(256) void sum_kernel(
    const u16* __restrict__ e_upd, const int* __restrict__ off,
    const int* __restrict__ eid, float* __restrict__ e_sum)
{
  const int grp = threadIdx.x >> 4, l16 = threadIdx.x & 15;
  const int n = blockIdx.x * 16 + grp;   // grid 3125 * 16 = 50000 exact
  float4 a = {0.f, 0.f, 0.f, 0.f};
  const int s0 = off[n], s1 = off[n + 1];
  for (int s = s0; s < s1; ++s) {
    int e = eid[s];
    ushort4 v = *reinterpret_cast<const ushort4*>(&e_upd[(size_t)e * 64 + l16 * 4]);
    a.x += bf2f(v.x); a.y += bf2f(v.y);
    a.z += bf2f(v.z); a.w += bf2f(v.w);
  }
  *reinterpret_cast<float4*>(&e_sum[(size_t)n * 64 + l16 * 4]) = a;
}

// ---------------- node MLP + degree gate ----------------
#define SA_N 200
#define SH   264

__global__ __launch_bounds__(256) void node_kernel(
    const float* __restrict__ nf, const float* __restrict__ e_sum,
    const int* __restrict__ hist,
    const u16* __restrict__ w1, const float* __restrict__ b1,
    const u16* __restrict__ w2, const float* __restrict__ b2,
    float* __restrict__ hout)
{
  __shared__ u16 A[64 * SH];
  const int tid = threadIdx.x;
  const int n0 = blockIdx.x * 64;

  const float4* nf4 = reinterpret_cast<const float4*>(nf);
  const float4* es4 = reinterpret_cast<const float4*>(e_sum);

  #pragma unroll
  for (int p = 0; p < 8; ++p) {
    int i = p * 256 + tid;
    int row = i >> 5, c4 = i & 31;
    int rg = min(n0 + row, N_NODES - 1);
    float4 v = nf4[(size_t)rg * 32 + c4];
    st_bf4(&A[row * SA_N + c4 * 4], v);
  }
  #pragma unroll
  for (int p = 0; p < 4; ++p) {
    int i = p * 256 + tid;
    int row = i >> 4, c4 = i & 15;
    int rg = min(n0 + row, N_NODES - 1);
    float4 v = es4[(size_t)rg * 16 + c4];
    st_bf4(&A[row * SA_N + 128 + c4 * 4], v);
  }
  __syncthreads();

  const int wave = tid >> 6, lane = tid & 63;
  const int lr = lane & 15;
  const int lk = (lane >> 4) * 8;

  f32x4 acc[4][4] = {};
  for (int kb = 0; kb < K_N / 32; ++kb) {
    const int ko = kb * 32 + lk;
    bf16x8 a[4], b[4];
    #pragma unroll
    for (int mt = 0; mt < 4; ++mt)
      a[mt] = *reinterpret_cast<const bf16x8*>(&A[(mt * 16 + lr) * SA_N + ko]);
    #pragma unroll
    for (int nt = 0; nt < 4; ++nt)
      b[nt] = *reinterpret_cast<const bf16x8*>(&w1[(size_t)(wave * 64 + nt * 16 + lr) * K_N + ko]);
    #pragma unroll
    for (int mt = 0; mt < 4; ++mt)
      #pragma unroll
      for (int nt = 0; nt < 4; ++nt)
        acc[mt][nt] = MFMA16(a[mt], b[nt], acc[mt][nt], 0, 0, 0);
  }
  __syncthreads();

  u16* H = A;
  #pragma unroll
  for (int mt = 0; mt < 4; ++mt)
    #pragma unroll
    for (int nt = 0; nt < 4; ++nt) {
      int col = wave * 64 + nt * 16 + lr;
      float bias = b1[col];
      #pragma unroll
      for (int j = 0; j < 4; ++j) {
        int row = mt * 16 + (lane >> 4) * 4 + j;
        float h = acc[mt][nt][j] + bias;
        H[row * SH + col] = f2bf(h > 0.f ? h : 0.f);
      }
    }
  __syncthreads();

  f32x4 acc2[8] = {};
  for (int kb = 0; kb < HIDDEN / 32; ++kb) {
    const int ko = kb * 32 + lk;
    bf16x8 a = *reinterpret_cast<const bf16x8*>(&H[(wave * 16 + lr) * SH + ko]);
    #pragma unroll
    for (int nt = 0; nt < 8; ++nt) {
      bf16x8 b = *reinterpret_cast<const bf16x8*>(&w2[(size_t)(nt * 16 + lr) * HIDDEN + ko]);
      acc2[nt] = MFMA16(a, b, acc2[nt], 0, 0, 0);
    }
  }
  #pragma unroll
  for (int nt = 0; nt < 8; ++nt) {
    int col = nt * 16 + lr;
    float bias = b2[col];
    #pragma unroll
    for (int j = 0; j < 4; ++j) {
      int row = wave * 16 + (lane >> 4) * 4 + j;
      int rg = n0 + row;
      if (rg < N_NODES) {
        float v = acc2[nt][j] + bias;
        hout[(size_t)rg * NODE_DIM + col] =
            (hist[rg] != 0) ? v : nf[(size_t)rg * NODE_DIM + col];
      }
    }
  }
}

// ---------------- launcher ----------------
extern "C" void kernel_launch(void* const* d_in, const int* in_sizes, int n_in,
                              void* d_out, int out_size, void* d_ws, size_t ws_size,
                              hipStream_t stream) {
  const float* nf  = (const float*)d_in[0];
  const float* ef  = (const float*)d_in[1];
  const int*   src = (const int*)d_in[2];
  const int*   dst = (const int*)d_in[3];
  const float* We1 = (const float*)d_in[4];
  const float* be1 = (const float*)d_in[5];
  const float* We2 = (const float*)d_in[6];
  const float* be2 = (const float*)d_in[7];
  const float* Wn1 = (const float*)d_in[8];
  const float* bn1 = (const float*)d_in[9];
  const float* Wn2 = (const float*)d_in[10];
  const float* bn2 = (const float*)d_in[11];

  float* hout = (float*)d_out;
  float* out_edge = hout + (size_t)N_NODES * NODE_DIM;

  char* ws = (char*)d_ws;
  int* hist    = (int*)ws;                       // 200,000 B
  int* off     = (int*)(ws + 200000);            // 200,004 B
  int* cursor  = (int*)(ws + 400016);            // 200,000 B
  int* eid     = (int*)(ws + 600016);            // 3,200,000 B
  u16* e_upd   = (u16*)(ws + 3800016);           // 102,400,000 B
  u16* w1y     = (u16*)(ws + 106200016);         // 163,840 B
  u16* w2y     = (u16*)(ws + 106363856);         // 32,768 B
  u16* wn1t    = (u16*)(ws + 106396624);         // 98,304 B
  u16* wn2t    = (u16*)(ws + 106494928);         // 65,536 B
  u16* nfb     = (u16*)(ws + 106560464);         // 12,800,000 B
  // e_sum (f32, 12.8MB) aliases nfb: nfb is only consumed by edge_mlp, which
  // completes (stream order) before sum_kernel writes e_sum.
  float* e_sum = (float*)(ws + 106560464);

  hipMemsetAsync(hist, 0, 200000, stream);
  prep_weights<<<512, 256, 0, stream>>>(We1, We2, Wn1, Wn2, nf,
                                        w1y, w2y, wn1t, wn2t, nfb);
  hist_kernel<<<(N_EDGES + 255) / 256, 256, 0, stream>>>(dst, hist);
  scan_kernel<<<1, SCAN_T, 0, stream>>>(hist, off, cursor);
  scatter_kernel<<<(N_EDGES + 255) / 256, 256, 0, stream>>>(dst, cursor, eid);

  edge_mlp<<<N_EDGES / 128, 256, 0, stream>>>(nfb, ef, src, dst, w1y, be1,
                                              w2y, be2, e_upd, out_edge);
  sum_kernel<<<N_NODES / 16, 256, 0, stream>>>(e_upd, off, eid, e_sum);
  node_kernel<<<(N_NODES + 63) / 64, 256, 0, stream>>>(nf, e_sum, hist,
                                                       wn1t, bn1, wn2t, bn2, hout);
}